// Round 3
// baseline (3120.939 us; speedup 1.0000x reference)
//
#include <hip/hip_runtime.h>
#include <math.h>

#define HP 264
#define WP 264
#define NPIX (HP*WP)          // 69696
#define CH 64
#define BATCH 4
#define BCN (BATCH*CH)        // 256
#define NROWS (BCN*HP)        // 67584
#define H0 256
#define W0 256

// ---------------- tables ----------------
// BX[x*64+k]  : fwd-x DFT. k=2m -> cos(2pi*x*m/264); k=2m+1 -> -sin(...)
// BI[k*264+x] : inv-x irfft. k=2m -> sc*cos; k=2m+1 -> -sc*sin; BI[1][x]=0.
// csY[y*64+j]  float2 (cos,sin) of 2pi*y*ky_j/264, ky_j = j<32 ? j : 200+j
// csYT[j*264+y] transposed
__global__ void init_tables(float* __restrict__ BX, float* __restrict__ BI,
                            float2* __restrict__ csY, float2* __restrict__ csYT) {
  int idx = blockIdx.x*256 + threadIdx.x;
  if (idx >= 264*64) return;
  const float w = 6.28318530717958647692f / 264.0f;
  {
    int x = idx >> 6, k = idx & 63;
    int m = k >> 1;
    float s, c; sincosf(w * (float)((x*m) % 264), &s, &c);
    BX[idx] = (k & 1) ? -s : c;
    float sc = (m ? 2.0f : 1.0f) / 69696.0f;
    float v = (k & 1) ? -sc*s : sc*c;
    if (k == 1) v = 0.f;
    BI[(size_t)k*264 + x] = v;
  }
  {
    int y = idx >> 6, j = idx & 63;
    int ky = (j < 32) ? j : (200 + j);
    float s, c; sincosf(w * (float)((y*ky) % 264), &s, &c);
    csY[y*64 + j] = make_float2(c, s);
    csYT[j*264 + y] = make_float2(c, s);
  }
}

// transpose mlp_w2: [3][64][128] -> W2T [3][128][64]
__global__ void transpose_w2(const float* __restrict__ W2, float* __restrict__ W2T) {
  int idx = blockIdx.x*256 + threadIdx.x;
  if (idx >= 3*128*64) return;
  int k = idx >> 13;
  int r = idx & 8191;
  int j = r >> 6, co = r & 63;
  W2T[idx] = W2[k*8192 + co*128 + j];
}

__device__ __forceinline__ float gelu_erf(float v) {
  return 0.5f * v * (1.0f + erff(v * 0.70710678118654752440f));
}

// ---------------- lift ----------------
__global__ __launch_bounds__(256) void lift_kernel(
    const float* __restrict__ xin,
    const float* __restrict__ w1, const float* __restrict__ b1,
    const float* __restrict__ w2, const float* __restrict__ b2,
    float* __restrict__ xbuf) {
  int b = blockIdx.y;
  int flat = blockIdx.x*256 + threadIdx.x;
  if (flat >= NPIX) return;
  int y = flat / WP, x = flat - y*WP;
  float* outp = xbuf + (size_t)b*CH*NPIX + flat;
  if (y >= H0 || x >= W0) {
    for (int c = 0; c < CH; ++c) outp[c*NPIX] = 0.f;
    return;
  }
  float in[5];
  const float* xb = xin + ((size_t)b*3)*H0*W0 + y*W0 + x;
  in[0] = xb[0];
  in[1] = xb[H0*W0];
  in[2] = xb[2*H0*W0];
  in[3] = (float)y * (1.0f/255.0f);
  in[4] = (float)x * (1.0f/255.0f);
  float t[32];
  #pragma unroll
  for (int h = 0; h < 32; ++h) {
    float s = b1[h];
    #pragma unroll
    for (int i = 0; i < 5; ++i) s += w1[h*5+i]*in[i];
    t[h] = gelu_erf(s);
  }
  for (int c = 0; c < CH; ++c) {
    float s = b2[c];
    #pragma unroll
    for (int h = 0; h < 32; ++h) s += w2[c*32+h]*t[h];
    outp[c*NPIX] = s;
  }
}

// ---------------- fused conv1x1(64->64) -> mlp1(64->128)+gelu -> mlp2(128->64)
// One PIXEL per thread. x/t1/out in VGPRs; all weights via contiguous
// wave-uniform scalar loads (s_load_dwordx16). Zero LDS.
__global__ __launch_bounds__(256) void convmlp_kernel(
    const float* __restrict__ X, float* __restrict__ Hb,
    const float* __restrict__ Wc, const float* __restrict__ cb,
    const float* __restrict__ W1, const float* __restrict__ b1,
    const float* __restrict__ W2T, const float* __restrict__ b2) {
  int b = blockIdx.y;
  int pix = blockIdx.x*256 + threadIdx.x;
  int pp = (pix < NPIX) ? pix : (NPIX - 1);
  const float* xb = X + (size_t)b*CH*NPIX + pp;
  float xv[64];
  #pragma unroll
  for (int ci = 0; ci < 64; ++ci) xv[ci] = xb[(size_t)ci*NPIX];
  // stage 1: conv 64->64
  float t1[64];
  #pragma unroll 1
  for (int co = 0; co < 64; ++co) {
    float a = cb[co];
    const float* w = Wc + co*64;
    #pragma unroll
    for (int ci = 0; ci < 64; ++ci) a = fmaf(xv[ci], w[ci], a);
    t1[co] = a;
  }
  // stages 2+3 fused: stream j over the 128 hidden units
  float out[64];
  #pragma unroll
  for (int co = 0; co < 64; ++co) out[co] = b2[co];
  #pragma unroll 1
  for (int j = 0; j < 128; ++j) {
    float g = b1[j];
    const float* w1r = W1 + j*64;
    #pragma unroll
    for (int ci = 0; ci < 64; ++ci) g = fmaf(t1[ci], w1r[ci], g);
    g = gelu_erf(g);
    const float* w2r = W2T + j*64;
    #pragma unroll
    for (int co = 0; co < 64; ++co) out[co] = fmaf(g, w2r[co], out[co]);
  }
  if (pix < NPIX) {
    float* hb = Hb + (size_t)b*CH*NPIX + pp;
    #pragma unroll
    for (int co = 0; co < 64; ++co) hb[(size_t)co*NPIX] = out[co];
  }
}

// ---------------- fwd-x DFT: F1[r][k] = sum_x X[r][x]*BX[x][k]
__global__ __launch_bounds__(128) void fwd_x_kernel(const float* __restrict__ X,
    float* __restrict__ F1, const float* __restrict__ BX) {
  int r = blockIdx.x*128 + threadIdx.x;
  const float* xr = X + (size_t)r*264;
  float acc[64];
  #pragma unroll
  for (int k = 0; k < 64; ++k) acc[k] = 0.f;
  float4 u = ((const float4*)xr)[0];
  float4 v = ((const float4*)xr)[1];
  #pragma unroll 1
  for (int xc = 0; xc < 33; ++xc) {
    int nc = (xc < 32) ? xc + 1 : 32;
    float4 nu = ((const float4*)xr)[nc*2];
    float4 nv = ((const float4*)xr)[nc*2+1];
    float xvv[8] = {u.x,u.y,u.z,u.w,v.x,v.y,v.z,v.w};
    #pragma unroll
    for (int i = 0; i < 8; ++i) {
      const float* B = BX + (xc*8+i)*64;
      #pragma unroll
      for (int k = 0; k < 64; ++k) acc[k] = fmaf(xvv[i], B[k], acc[k]);
    }
    u = nu; v = nv;
  }
  float* fr = F1 + (size_t)r*64;
  #pragma unroll
  for (int q = 0; q < 16; ++q)
    ((float4*)fr)[q] = make_float4(acc[4*q],acc[4*q+1],acc[4*q+2],acc[4*q+3]);
}

// ---------------- fwd-y DFT
__global__ __launch_bounds__(256) void fwd_y_kernel(const float* __restrict__ F1,
    float* __restrict__ F2, const float2* __restrict__ csY) {
  __shared__ float sT[4][64][68];
  int tid = threadIdx.x, lane = tid & 63, w = tid >> 6;
  int bc = blockIdx.x;
  float acc[64];
  #pragma unroll
  for (int k = 0; k < 64; ++k) acc[k] = 0.f;
  const float* f1b = F1 + (size_t)bc*264*64;
  for (int y = w*66; y < (w+1)*66; ++y) {
    float2 cs = csY[y*64 + lane];
    float c = cs.x, s = cs.y, ns = -s;
    const float* fr = f1b + y*64;
    #pragma unroll
    for (int kx = 0; kx < 32; ++kx) {
      float fre = fr[2*kx], fim = fr[2*kx+1];
      acc[2*kx]   = fmaf(c, fre, fmaf(s,  fim, acc[2*kx]));
      acc[2*kx+1] = fmaf(c, fim, fmaf(ns, fre, acc[2*kx+1]));
    }
  }
  #pragma unroll
  for (int k = 0; k < 64; ++k) sT[w][lane][k] = acc[k];
  __syncthreads();
  int j = tid >> 2, k0 = (tid & 3) * 16;
  float* out = F2 + (size_t)bc*4096 + j*64 + k0;
  #pragma unroll
  for (int k = 0; k < 16; ++k)
    out[k] = sT[0][j][k0+k] + sT[1][j][k0+k] + sT[2][j][k0+k] + sT[3][j][k0+k];
}

// ---------------- per-mode channel mixing
__global__ __launch_bounds__(256) void mix_kernel(const float2* __restrict__ F2,
    float2* __restrict__ S,
    const float* __restrict__ w1r, const float* __restrict__ w1i,
    const float* __restrict__ w2r, const float* __restrict__ w2i) {
  int tid = threadIdx.x;
  int m = tid & 63;
  int cl = tid >> 6;
  int mode = blockIdx.x*64 + m;
  int co = blockIdx.y*4 + cl;
  int b = blockIdx.z;
  int moff = mode & 1023;
  const float* wr = ((mode < 1024) ? w1r : w2r) + co*1024 + moff;
  const float* wi = ((mode < 1024) ? w1i : w2i) + co*1024 + moff;
  const float2* f2 = F2 + (size_t)b*CH*2048 + mode;
  float sr = 0.f, si = 0.f;
  for (int ci = 0; ci < 64; ++ci) {
    float2 f = f2[(size_t)ci*2048];
    float wrv = wr[(size_t)ci*65536];
    float wiv = wi[(size_t)ci*65536];
    sr += f.x*wrv - f.y*wiv;
    si += f.x*wiv + f.y*wrv;
  }
  S[((size_t)b*CH + co)*2048 + mode] = make_float2(sr, si);
}

// ---------------- inv-y DFT
__global__ __launch_bounds__(64) void inv_y_kernel(const float* __restrict__ S,
    float* __restrict__ Z, const float2* __restrict__ csYT) {
  int bc = blockIdx.y;
  int y = blockIdx.x*64 + threadIdx.x;
  int yy = (y < 264) ? y : 263;
  float acc[64];
  #pragma unroll
  for (int k = 0; k < 64; ++k) acc[k] = 0.f;
  const float* sb = S + (size_t)bc*4096;
  for (int j = 0; j < 64; ++j) {
    float2 cs = csYT[j*264 + yy];
    float c = cs.x, s = cs.y, ns = -s;
    const float* sr = sb + j*64;
    #pragma unroll
    for (int kx = 0; kx < 32; ++kx) {
      float sre = sr[2*kx], sim = sr[2*kx+1];
      acc[2*kx]   = fmaf(c, sre, fmaf(ns, sim, acc[2*kx]));
      acc[2*kx+1] = fmaf(s, sre, fmaf(c,  sim, acc[2*kx+1]));
    }
  }
  if (y < 264) {
    float* zr = Z + ((size_t)bc*264 + y)*64;
    #pragma unroll
    for (int q = 0; q < 16; ++q)
      ((float4*)zr)[q] = make_float4(acc[4*q],acc[4*q+1],acc[4*q+2],acc[4*q+3]);
  }
}

// ---------------- inv-x irfft + Hb add + store (crop on last layer)
__global__ __launch_bounds__(128) void inv_x_kernel(const float* __restrict__ Z,
    const float* __restrict__ Hb, float* __restrict__ Xout, float* __restrict__ Dout,
    const float* __restrict__ BI, int last) {
  int r = blockIdx.x*128 + threadIdx.x;
  int xh = blockIdx.y;
  float a[64];
  const float4* zp = (const float4*)(Z + (size_t)r*64);
  #pragma unroll
  for (int q = 0; q < 16; ++q) {
    float4 t = zp[q];
    a[4*q] = t.x; a[4*q+1] = t.y; a[4*q+2] = t.z; a[4*q+3] = t.w;
  }
  int y = r % 264;
  int bc = r / 264;
  const float* hbr = Hb + (size_t)r*264;
  float* xo = Xout + (size_t)r*264;
  float* dor = Dout + ((size_t)bc*256 + y)*256;
  #pragma unroll 1
  for (int cch = 0; cch < 4; ++cch) {
    int x0 = xh*128 + cch*32;
    float acc[32];
    #pragma unroll
    for (int s = 0; s < 32; ++s) acc[s] = 0.f;
    #pragma unroll
    for (int k = 0; k < 64; ++k) {
      const float* B = BI + (size_t)k*264 + x0;
      #pragma unroll
      for (int s = 0; s < 32; ++s) acc[s] = fmaf(a[k], B[s], acc[s]);
    }
    if (!last) {
      #pragma unroll
      for (int q = 0; q < 8; ++q) {
        float4 h = ((const float4*)(hbr + x0))[q];
        ((float4*)(xo + x0))[q] =
          make_float4(h.x+acc[4*q], h.y+acc[4*q+1], h.z+acc[4*q+2], h.w+acc[4*q+3]);
      }
    } else if (y < 256) {
      #pragma unroll
      for (int q = 0; q < 8; ++q) {
        float4 h = ((const float4*)(hbr + x0))[q];
        ((float4*)(dor + x0))[q] =
          make_float4(h.x+acc[4*q], h.y+acc[4*q+1], h.z+acc[4*q+2], h.w+acc[4*q+3]);
      }
    }
  }
  if (xh == 1 && !last) {
    float acc[8];
    #pragma unroll
    for (int s = 0; s < 8; ++s) acc[s] = 0.f;
    #pragma unroll
    for (int k = 0; k < 64; ++k) {
      const float* B = BI + (size_t)k*264 + 256;
      #pragma unroll
      for (int s = 0; s < 8; ++s) acc[s] = fmaf(a[k], B[s], acc[s]);
    }
    #pragma unroll
    for (int q = 0; q < 2; ++q) {
      float4 h = ((const float4*)(hbr + 256))[q];
      ((float4*)(xo + 256))[q] =
        make_float4(h.x+acc[4*q], h.y+acc[4*q+1], h.z+acc[4*q+2], h.w+acc[4*q+3]);
    }
  }
}

extern "C" void kernel_launch(void* const* d_in, const int* in_sizes, int n_in,
                              void* d_out, int out_size, void* d_ws, size_t ws_size,
                              hipStream_t stream) {
  (void)in_sizes; (void)n_in; (void)out_size; (void)ws_size;
  const float* x_in   = (const float*)d_in[0];
  const float* lw1    = (const float*)d_in[1];
  const float* lb1    = (const float*)d_in[2];
  const float* lw2    = (const float*)d_in[3];
  const float* lb2    = (const float*)d_in[4];
  const float* conv_w = (const float*)d_in[5];
  const float* conv_b = (const float*)d_in[6];
  const float* mlp_w1 = (const float*)d_in[7];
  const float* mlp_b1 = (const float*)d_in[8];
  const float* mlp_w2 = (const float*)d_in[9];
  const float* mlp_b2 = (const float*)d_in[10];
  const float* sw1r   = (const float*)d_in[11];
  const float* sw1i   = (const float*)d_in[12];
  const float* sw2r   = (const float*)d_in[13];
  const float* sw2i   = (const float*)d_in[14];
  float* dout = (float*)d_out;

  float* ws = (float*)d_ws;
  size_t off = 0;
  float*  xbuf = ws + off;          off += (size_t)BCN*NPIX;
  float*  hbuf = ws + off;          off += (size_t)BCN*NPIX;
  float*  F1   = ws + off;          off += (size_t)NROWS*64;   // also Z
  float*  F2   = ws + off;          off += (size_t)BCN*4096;
  float*  S    = ws + off;          off += (size_t)BCN*4096;
  float*  BX   = ws + off;          off += 264*64;
  float*  BI   = ws + off;          off += 264*64;
  float2* csY  = (float2*)(ws+off); off += 264*64*2;
  float2* csYT = (float2*)(ws+off); off += 264*64*2;
  float*  W2T  = ws + off;          off += 3*128*64;

  init_tables<<<66, 256, 0, stream>>>(BX, BI, csY, csYT);
  transpose_w2<<<96, 256, 0, stream>>>(mlp_w2, W2T);
  lift_kernel<<<dim3(273, 4), 256, 0, stream>>>(x_in, lw1, lb1, lw2, lb2, xbuf);

  for (int k = 0; k < 3; ++k) {
    convmlp_kernel<<<dim3(273, 4), 256, 0, stream>>>(xbuf, hbuf,
        conv_w + k*4096, conv_b + k*64,
        mlp_w1 + k*8192, mlp_b1 + k*128,
        W2T + k*8192, mlp_b2 + k*64);
    fwd_x_kernel<<<528, 128, 0, stream>>>(xbuf, F1, BX);
    fwd_y_kernel<<<256, 256, 0, stream>>>(F1, F2, csY);
    mix_kernel<<<dim3(32, 16, 4), 256, 0, stream>>>((const float2*)F2, (float2*)S,
        sw1r + (size_t)k*4194304, sw1i + (size_t)k*4194304,
        sw2r + (size_t)k*4194304, sw2i + (size_t)k*4194304);
    inv_y_kernel<<<dim3(5, 256), 64, 0, stream>>>(S, F1, csYT);
    inv_x_kernel<<<dim3(528, 2), 128, 0, stream>>>(F1, hbuf, xbuf, dout, BI, (k==2)?1:0);
  }
}

// Round 4
// 1867.818 us; speedup vs baseline: 1.6709x; 1.6709x over previous
//
#include <hip/hip_runtime.h>
#include <math.h>

#define HP 264
#define WP 264
#define NPIX (HP*WP)          // 69696
#define CH 64
#define BATCH 4
#define BCN (BATCH*CH)        // 256
#define NROWS (BCN*HP)        // 67584
#define H0 256
#define W0 256

// ---------------- tables ----------------
__global__ void init_tables(float* __restrict__ BX, float* __restrict__ BI,
                            float2* __restrict__ csY, float2* __restrict__ csYT) {
  int idx = blockIdx.x*256 + threadIdx.x;
  if (idx >= 264*64) return;
  const float w = 6.28318530717958647692f / 264.0f;
  {
    int x = idx >> 6, k = idx & 63;
    int m = k >> 1;
    float s, c; sincosf(w * (float)((x*m) % 264), &s, &c);
    BX[idx] = (k & 1) ? -s : c;
    float sc = (m ? 2.0f : 1.0f) / 69696.0f;
    float v = (k & 1) ? -sc*s : sc*c;
    if (k == 1) v = 0.f;
    BI[(size_t)k*264 + x] = v;
  }
  {
    int y = idx >> 6, j = idx & 63;
    int ky = (j < 32) ? j : (200 + j);
    float s, c; sincosf(w * (float)((y*ky) % 264), &s, &c);
    csY[y*64 + j] = make_float2(c, s);
    csYT[j*264 + y] = make_float2(c, s);
  }
}

// Pre-transpose weights so per-ci wave-uniform weight fetches are CONTIGUOUS:
// WcT[k][ci][co]  <- conv_w[k][co][ci]
// W1T[k][ci][j]   <- mlp_w1[k][j][ci]
// W2T[k][j][co]   <- mlp_w2[k][co][j]
__global__ void transpose_weights(const float* __restrict__ Wc,
                                  const float* __restrict__ W1,
                                  const float* __restrict__ W2,
                                  float* __restrict__ WcT,
                                  float* __restrict__ W1T,
                                  float* __restrict__ W2T) {
  int idx = blockIdx.x*256 + threadIdx.x;
  if (idx < 3*4096) {
    int k = idx/4096, r = idx%4096, ci = r>>6, co = r&63;
    WcT[idx] = Wc[k*4096 + co*64 + ci];
  }
  if (idx < 3*8192) {
    int k = idx/8192, r = idx%8192, ci = r>>7, j = r&127;
    W1T[idx] = W1[k*8192 + j*64 + ci];
  }
  if (idx < 3*8192) {
    int k = idx/8192, r = idx%8192, j = r>>6, co = r&63;
    W2T[idx] = W2[k*8192 + co*128 + j];
  }
}

__device__ __forceinline__ float gelu_erf(float v) {
  return 0.5f * v * (1.0f + erff(v * 0.70710678118654752440f));
}

// ---------------- lift ----------------
__global__ __launch_bounds__(256) void lift_kernel(
    const float* __restrict__ xin,
    const float* __restrict__ w1, const float* __restrict__ b1,
    const float* __restrict__ w2, const float* __restrict__ b2,
    float* __restrict__ xbuf) {
  int b = blockIdx.y;
  int flat = blockIdx.x*256 + threadIdx.x;
  if (flat >= NPIX) return;
  int y = flat / WP, x = flat - y*WP;
  float* outp = xbuf + (size_t)b*CH*NPIX + flat;
  if (y >= H0 || x >= W0) {
    for (int c = 0; c < CH; ++c) outp[c*NPIX] = 0.f;
    return;
  }
  float in[5];
  const float* xb = xin + ((size_t)b*3)*H0*W0 + y*W0 + x;
  in[0] = xb[0];
  in[1] = xb[H0*W0];
  in[2] = xb[2*H0*W0];
  in[3] = (float)y * (1.0f/255.0f);
  in[4] = (float)x * (1.0f/255.0f);
  float t[32];
  #pragma unroll
  for (int h = 0; h < 32; ++h) {
    float s = b1[h];
    #pragma unroll
    for (int i = 0; i < 5; ++i) s += w1[h*5+i]*in[i];
    t[h] = gelu_erf(s);
  }
  for (int c = 0; c < CH; ++c) {
    float s = b2[c];
    #pragma unroll
    for (int h = 0; h < 32; ++h) s += w2[c*32+h]*t[h];
    outp[c*NPIX] = s;
  }
}

// ---------------- fused conv1x1(64->64) -> mlp1(64->128)+gelu -> mlp2(128->64)
// 64-pixel LDS tile (round-2 structure), but weights pre-transposed so each
// ci-iteration's wave-uniform weight group is one contiguous s_load_dwordx16.
__global__ __launch_bounds__(256) void convmlp_kernel(
    const float* __restrict__ X, float* __restrict__ Hb,
    const float* __restrict__ WcT, const float* __restrict__ cb,
    const float* __restrict__ W1T, const float* __restrict__ b1,
    const float* __restrict__ W2T, const float* __restrict__ b2) {
  __shared__ float sA[128*64];   // input tile (ci-major), later gelu tile (j-major)
  __shared__ float sB[64*64];    // conv output tile
  int blk = blockIdx.x;
  int b = blk / 1089;
  int flat0 = (blk - b*1089) * 64;
  int tid = threadIdx.x;
  int p = tid & 63;
  int cg = __builtin_amdgcn_readfirstlane(tid >> 6);  // 0..3 wave-uniform
  const float* xb = X + (size_t)b*CH*NPIX + flat0;
  #pragma unroll
  for (int i = 0; i < 16; ++i) {
    int idx = i*256 + tid;
    int ci = idx >> 6, pp = idx & 63;
    sA[idx] = xb[ci*NPIX + pp];
  }
  __syncthreads();
  // stage 1: conv 64->64; weights WcT[ci][cg*16..+16) contiguous
  float acc0[16];
  #pragma unroll
  for (int i = 0; i < 16; ++i) acc0[i] = cb[cg*16+i];
  #pragma unroll 4
  for (int ci = 0; ci < 64; ++ci) {
    float xv = sA[ci*64+p];
    const float* w = WcT + ci*64 + cg*16;
    #pragma unroll
    for (int i = 0; i < 16; ++i) acc0[i] = fmaf(xv, w[i], acc0[i]);
  }
  #pragma unroll
  for (int i = 0; i < 16; ++i) sB[(cg*16+i)*64+p] = acc0[i];
  __syncthreads();
  // stage 2: mlp1 64->128 + gelu; weights W1T[ci][cg*32..+32) contiguous
  float a1[32];
  #pragma unroll
  for (int j = 0; j < 32; ++j) a1[j] = b1[cg*32+j];
  #pragma unroll 4
  for (int ci = 0; ci < 64; ++ci) {
    float xv = sB[ci*64+p];
    const float* w = W1T + ci*128 + cg*32;
    #pragma unroll
    for (int j = 0; j < 32; ++j) a1[j] = fmaf(xv, w[j], a1[j]);
  }
  #pragma unroll
  for (int j = 0; j < 32; ++j) sA[(cg*32+j)*64+p] = gelu_erf(a1[j]);
  __syncthreads();
  // stage 3: mlp2 128->64; weights W2T[j][cg*16..+16) contiguous
  float acc2[16];
  #pragma unroll
  for (int i = 0; i < 16; ++i) acc2[i] = b2[cg*16+i];
  #pragma unroll 4
  for (int j = 0; j < 128; ++j) {
    float xv = sA[j*64+p];
    const float* w = W2T + j*64 + cg*16;
    #pragma unroll
    for (int i = 0; i < 16; ++i) acc2[i] = fmaf(xv, w[i], acc2[i]);
  }
  float* hb = Hb + (size_t)b*CH*NPIX + flat0;
  #pragma unroll
  for (int i = 0; i < 16; ++i) hb[(cg*16+i)*NPIX + p] = acc2[i];
}

// ---------------- fwd-x DFT: F1[r][k] = sum_x X[r][x]*BX[x][k]
__global__ __launch_bounds__(128) void fwd_x_kernel(const float* __restrict__ X,
    float* __restrict__ F1, const float* __restrict__ BX) {
  int r = blockIdx.x*128 + threadIdx.x;
  const float* xr = X + (size_t)r*264;
  float acc[64];
  #pragma unroll
  for (int k = 0; k < 64; ++k) acc[k] = 0.f;
  float4 u = ((const float4*)xr)[0];
  float4 v = ((const float4*)xr)[1];
  #pragma unroll 1
  for (int xc = 0; xc < 33; ++xc) {
    int nc = (xc < 32) ? xc + 1 : 32;
    float4 nu = ((const float4*)xr)[nc*2];
    float4 nv = ((const float4*)xr)[nc*2+1];
    float xvv[8] = {u.x,u.y,u.z,u.w,v.x,v.y,v.z,v.w};
    #pragma unroll
    for (int i = 0; i < 8; ++i) {
      const float* B = BX + (xc*8+i)*64;
      #pragma unroll
      for (int k = 0; k < 64; ++k) acc[k] = fmaf(xvv[i], B[k], acc[k]);
    }
    u = nu; v = nv;
  }
  float* fr = F1 + (size_t)r*64;
  #pragma unroll
  for (int q = 0; q < 16; ++q)
    ((float4*)fr)[q] = make_float4(acc[4*q],acc[4*q+1],acc[4*q+2],acc[4*q+3]);
}

// ---------------- fwd-y DFT
__global__ __launch_bounds__(256) void fwd_y_kernel(const float* __restrict__ F1,
    float* __restrict__ F2, const float2* __restrict__ csY) {
  __shared__ float sT[4][64][68];
  int tid = threadIdx.x, lane = tid & 63, w = tid >> 6;
  int bc = blockIdx.x;
  float acc[64];
  #pragma unroll
  for (int k = 0; k < 64; ++k) acc[k] = 0.f;
  const float* f1b = F1 + (size_t)bc*264*64;
  for (int y = w*66; y < (w+1)*66; ++y) {
    float2 cs = csY[y*64 + lane];
    float c = cs.x, s = cs.y, ns = -s;
    const float* fr = f1b + y*64;
    #pragma unroll
    for (int kx = 0; kx < 32; ++kx) {
      float fre = fr[2*kx], fim = fr[2*kx+1];
      acc[2*kx]   = fmaf(c, fre, fmaf(s,  fim, acc[2*kx]));
      acc[2*kx+1] = fmaf(c, fim, fmaf(ns, fre, acc[2*kx+1]));
    }
  }
  #pragma unroll
  for (int k = 0; k < 64; ++k) sT[w][lane][k] = acc[k];
  __syncthreads();
  int j = tid >> 2, k0 = (tid & 3) * 16;
  float* out = F2 + (size_t)bc*4096 + j*64 + k0;
  #pragma unroll
  for (int k = 0; k < 16; ++k)
    out[k] = sT[0][j][k0+k] + sT[1][j][k0+k] + sT[2][j][k0+k] + sT[3][j][k0+k];
}

// ---------------- per-mode channel mixing; weights read once, all 4 batch
// elements accumulated per thread.
__global__ __launch_bounds__(256) void mix_kernel(const float2* __restrict__ F2,
    float2* __restrict__ S,
    const float* __restrict__ w1r, const float* __restrict__ w1i,
    const float* __restrict__ w2r, const float* __restrict__ w2i) {
  int tid = threadIdx.x;
  int m = tid & 63;
  int cl = tid >> 6;
  int mode = blockIdx.x*64 + m;
  int co = blockIdx.y*4 + cl;
  int moff = mode & 1023;
  const float* wr = ((mode < 1024) ? w1r : w2r) + co*1024 + moff;
  const float* wi = ((mode < 1024) ? w1i : w2i) + co*1024 + moff;
  const float2* f2 = F2 + mode;
  float sr[4], si[4];
  #pragma unroll
  for (int b = 0; b < 4; ++b) { sr[b] = 0.f; si[b] = 0.f; }
  for (int ci = 0; ci < 64; ++ci) {
    float wrv = wr[(size_t)ci*65536];
    float wiv = wi[(size_t)ci*65536];
    #pragma unroll
    for (int b = 0; b < 4; ++b) {
      float2 f = f2[(size_t)(b*CH + ci)*2048];
      sr[b] = fmaf(f.x, wrv, fmaf(-f.y, wiv, sr[b]));
      si[b] = fmaf(f.x, wiv, fmaf( f.y, wrv, si[b]));
    }
  }
  #pragma unroll
  for (int b = 0; b < 4; ++b)
    S[((size_t)b*CH + co)*2048 + mode] = make_float2(sr[b], si[b]);
}

// ---------------- inv-y DFT
__global__ __launch_bounds__(64) void inv_y_kernel(const float* __restrict__ S,
    float* __restrict__ Z, const float2* __restrict__ csYT) {
  int bc = blockIdx.y;
  int y = blockIdx.x*64 + threadIdx.x;
  int yy = (y < 264) ? y : 263;
  float acc[64];
  #pragma unroll
  for (int k = 0; k < 64; ++k) acc[k] = 0.f;
  const float* sb = S + (size_t)bc*4096;
  for (int j = 0; j < 64; ++j) {
    float2 cs = csYT[j*264 + yy];
    float c = cs.x, s = cs.y, ns = -s;
    const float* sr = sb + j*64;
    #pragma unroll
    for (int kx = 0; kx < 32; ++kx) {
      float sre = sr[2*kx], sim = sr[2*kx+1];
      acc[2*kx]   = fmaf(c, sre, fmaf(ns, sim, acc[2*kx]));
      acc[2*kx+1] = fmaf(s, sre, fmaf(c,  sim, acc[2*kx+1]));
    }
  }
  if (y < 264) {
    float* zr = Z + ((size_t)bc*264 + y)*64;
    #pragma unroll
    for (int q = 0; q < 16; ++q)
      ((float4*)zr)[q] = make_float4(acc[4*q],acc[4*q+1],acc[4*q+2],acc[4*q+3]);
  }
}

// ---------------- inv-x irfft + Hb add + store (crop on last layer)
__global__ __launch_bounds__(128) void inv_x_kernel(const float* __restrict__ Z,
    const float* __restrict__ Hb, float* __restrict__ Xout, float* __restrict__ Dout,
    const float* __restrict__ BI, int last) {
  int r = blockIdx.x*128 + threadIdx.x;
  int xh = blockIdx.y;
  float a[64];
  const float4* zp = (const float4*)(Z + (size_t)r*64);
  #pragma unroll
  for (int q = 0; q < 16; ++q) {
    float4 t = zp[q];
    a[4*q] = t.x; a[4*q+1] = t.y; a[4*q+2] = t.z; a[4*q+3] = t.w;
  }
  int y = r % 264;
  int bc = r / 264;
  const float* hbr = Hb + (size_t)r*264;
  float* xo = Xout + (size_t)r*264;
  float* dor = Dout + ((size_t)bc*256 + y)*256;
  #pragma unroll 1
  for (int cch = 0; cch < 4; ++cch) {
    int x0 = xh*128 + cch*32;
    float acc[32];
    #pragma unroll
    for (int s = 0; s < 32; ++s) acc[s] = 0.f;
    #pragma unroll
    for (int k = 0; k < 64; ++k) {
      const float* B = BI + (size_t)k*264 + x0;
      #pragma unroll
      for (int s = 0; s < 32; ++s) acc[s] = fmaf(a[k], B[s], acc[s]);
    }
    if (!last) {
      #pragma unroll
      for (int q = 0; q < 8; ++q) {
        float4 h = ((const float4*)(hbr + x0))[q];
        ((float4*)(xo + x0))[q] =
          make_float4(h.x+acc[4*q], h.y+acc[4*q+1], h.z+acc[4*q+2], h.w+acc[4*q+3]);
      }
    } else if (y < 256) {
      #pragma unroll
      for (int q = 0; q < 8; ++q) {
        float4 h = ((const float4*)(hbr + x0))[q];
        ((float4*)(dor + x0))[q] =
          make_float4(h.x+acc[4*q], h.y+acc[4*q+1], h.z+acc[4*q+2], h.w+acc[4*q+3]);
      }
    }
  }
  if (xh == 1 && !last) {
    float acc[8];
    #pragma unroll
    for (int s = 0; s < 8; ++s) acc[s] = 0.f;
    #pragma unroll
    for (int k = 0; k < 64; ++k) {
      const float* B = BI + (size_t)k*264 + 256;
      #pragma unroll
      for (int s = 0; s < 8; ++s) acc[s] = fmaf(a[k], B[s], acc[s]);
    }
    #pragma unroll
    for (int q = 0; q < 2; ++q) {
      float4 h = ((const float4*)(hbr + 256))[q];
      ((float4*)(xo + 256))[q] =
        make_float4(h.x+acc[4*q], h.y+acc[4*q+1], h.z+acc[4*q+2], h.w+acc[4*q+3]);
    }
  }
}

extern "C" void kernel_launch(void* const* d_in, const int* in_sizes, int n_in,
                              void* d_out, int out_size, void* d_ws, size_t ws_size,
                              hipStream_t stream) {
  (void)in_sizes; (void)n_in; (void)out_size; (void)ws_size;
  const float* x_in   = (const float*)d_in[0];
  const float* lw1    = (const float*)d_in[1];
  const float* lb1    = (const float*)d_in[2];
  const float* lw2    = (const float*)d_in[3];
  const float* lb2    = (const float*)d_in[4];
  const float* conv_w = (const float*)d_in[5];
  const float* conv_b = (const float*)d_in[6];
  const float* mlp_w1 = (const float*)d_in[7];
  const float* mlp_b1 = (const float*)d_in[8];
  const float* mlp_w2 = (const float*)d_in[9];
  const float* mlp_b2 = (const float*)d_in[10];
  const float* sw1r   = (const float*)d_in[11];
  const float* sw1i   = (const float*)d_in[12];
  const float* sw2r   = (const float*)d_in[13];
  const float* sw2i   = (const float*)d_in[14];
  float* dout = (float*)d_out;

  float* ws = (float*)d_ws;
  size_t off = 0;
  float*  xbuf = ws + off;          off += (size_t)BCN*NPIX;
  float*  hbuf = ws + off;          off += (size_t)BCN*NPIX;
  float*  F1   = ws + off;          off += (size_t)NROWS*64;   // also Z
  float*  F2   = ws + off;          off += (size_t)BCN*4096;
  float*  S    = ws + off;          off += (size_t)BCN*4096;
  float*  BX   = ws + off;          off += 264*64;
  float*  BI   = ws + off;          off += 264*64;
  float2* csY  = (float2*)(ws+off); off += 264*64*2;
  float2* csYT = (float2*)(ws+off); off += 264*64*2;
  float*  WcT  = ws + off;          off += 3*4096;
  float*  W1T  = ws + off;          off += 3*8192;
  float*  W2T  = ws + off;          off += 3*8192;

  init_tables<<<66, 256, 0, stream>>>(BX, BI, csY, csYT);
  transpose_weights<<<96, 256, 0, stream>>>(conv_w, mlp_w1, mlp_w2, WcT, W1T, W2T);
  lift_kernel<<<dim3(273, 4), 256, 0, stream>>>(x_in, lw1, lb1, lw2, lb2, xbuf);

  for (int k = 0; k < 3; ++k) {
    convmlp_kernel<<<4356, 256, 0, stream>>>(xbuf, hbuf,
        WcT + k*4096, conv_b + k*64,
        W1T + k*8192, mlp_b1 + k*128,
        W2T + k*8192, mlp_b2 + k*64);
    fwd_x_kernel<<<528, 128, 0, stream>>>(xbuf, F1, BX);
    fwd_y_kernel<<<256, 256, 0, stream>>>(F1, F2, csY);
    mix_kernel<<<dim3(32, 16), 256, 0, stream>>>((const float2*)F2, (float2*)S,
        sw1r + (size_t)k*4194304, sw1i + (size_t)k*4194304,
        sw2r + (size_t)k*4194304, sw2i + (size_t)k*4194304);
    inv_y_kernel<<<dim3(5, 256), 64, 0, stream>>>(S, F1, csYT);
    inv_x_kernel<<<dim3(528, 2), 128, 0, stream>>>(F1, hbuf, xbuf, dout, BI, (k==2)?1:0);
  }
}